// Round 17
// baseline (88.572 us; speedup 1.0000x reference)
//
#include <hip/hip_runtime.h>

#define N 8192
#define NCLS 81
#define PAD 300
#define NPANEL 16
#define PANW 512

typedef unsigned long long u64;

__device__ __forceinline__ void gload_lds16(const void* g, void* l) {
  __builtin_amdgcn_global_load_lds(
      (const __attribute__((address_space(1))) unsigned int*)g,
      (__attribute__((address_space(3))) unsigned int*)l, 16, 0, 0);
}

// ---------------- K1: decode, 8 lanes per row + ctr/rank zero ----------------
__global__ __launch_bounds__(256) void decode_kernel(
    const float* __restrict__ meta, const float* __restrict__ deltas,
    const float* __restrict__ proposals, const float* __restrict__ scores,
    float4* __restrict__ sel, u64* __restrict__ keys, int* __restrict__ rank,
    int* __restrict__ ctr) {
  int tid = threadIdx.x;
  if (blockIdx.x == 0 && tid < 16) ctr[tid] = 0;  // col-panel counters
  int row = blockIdx.x * 32 + (tid >> 3);
  int sub = tid & 7;
  const float* srow = scores + (size_t)row * NCLS;
  float bs = -1e30f, ms = -1e30f;
  int best = 0;
  for (int c = sub; c < NCLS; c += 8) {
    float v = srow[c];
    if (v > bs) { bs = v; best = c; }
    if (c > 0) ms = fmaxf(ms, v);
  }
#pragma unroll
  for (int d = 1; d < 8; d <<= 1) {
    float ob = __shfl_xor(bs, d);
    int oi = __shfl_xor(best, d);
    float om = __shfl_xor(ms, d);
    if (ob > bs || (ob == bs && oi < best)) { bs = ob; best = oi; }
    ms = fmaxf(ms, om);
  }
  if (sub == 0) {
    float W = meta[1], sc = meta[2], H = meta[0];
    const float* p = proposals + row * 4;
    float x1 = p[0] / sc, y1 = p[1] / sc, x2 = p[2] / sc, y2 = p[3] / sc;
    float w = x2 - x1 + 1.0f, h = y2 - y1 + 1.0f;
    float cx = x1 + 0.5f * w, cy = y1 + 0.5f * h;
    float4 d4 = *(const float4*)(deltas + (size_t)row * (4 * NCLS) + best * 4);
    float pcx = d4.x * w + cx, pcy = d4.y * h + cy;
    float pw = expf(d4.z) * w, ph = expf(d4.w) * h;
    float lx = W - 1.0f, ly = H - 1.0f;
    float ox1 = fminf(fmaxf(pcx - 0.5f * pw, 0.0f), lx);
    float oy1 = fminf(fmaxf(pcy - 0.5f * ph, 0.0f), ly);
    float ox2 = fminf(fmaxf(pcx + 0.5f * pw, 0.0f), lx);
    float oy2 = fminf(fmaxf(pcy + 0.5f * ph, 0.0f), ly);
    sel[row] = make_float4(ox1, oy1, ox2, oy2);
    keys[row] = ((u64)(~__float_as_uint(ms)) << 32) | (unsigned)row;
    rank[row] = 0;
  }
}

// ---------------- K2a: brute-force rank, LDS-tiled ----------------
__global__ __launch_bounds__(256) void rank_kernel(
    const u64* __restrict__ keys, int* __restrict__ rank) {
  __shared__ u64 kt[256];
  int tid = threadIdx.x;
  int i = blockIdx.x * 256 + tid;
  kt[tid] = keys[blockIdx.y * 256 + tid];
  u64 ki = keys[i];
  __syncthreads();
  int c = 0;
#pragma unroll 8
  for (int t = 0; t < 256; ++t) c += (kt[t] < ki);
  atomicAdd(&rank[i], c);
}

// ---------------- K2b: scatter into sorted order (+ exact area) ----------------
__global__ __launch_bounds__(256) void scatter_kernel(
    const int* __restrict__ rank, const float4* __restrict__ sel,
    int* __restrict__ sortedIdx, float4* __restrict__ sortedBoxes,
    float* __restrict__ sortedArea) {
  int i = blockIdx.x * 256 + threadIdx.x;
  int r = rank[i];
  float4 b = sel[i];
  sortedIdx[r] = i;
  sortedBoxes[r] = b;
  sortedArea[r] = fmaxf(b.z - b.x, 0.0f) * fmaxf(b.w - b.y, 0.0f);
}

// ---------------- K3+K4 fused: mask workers + gated greedy scan ----------------
// R15 structure (cb-major wavefront, unroll-2 workers, agent-scope coherence)
// with the scan keep-loop upgraded to O(1) empty-word skip: wm =
// ballot(~remv != 0) & 0xFF maps words that still hold candidates; next word
// = ffs(wm). Consumed self-bits are OR'd into the owning lane's remv (a
// keep's own bit appears in no mask row); suppressed candidates' bits arrive
// via the suppressor's sA. This removes ~2048 per-empty-word iterations
// (~15-25µs) that R13-R15 paid. Half-2 slab wait is lazily triggered on
// first w>=4. Coherence/gates unchanged (proven): expected[cp] = 16*cp + 12.
__global__ __launch_bounds__(256) void mask_scan_kernel(
    const float4* __restrict__ sboxes, const float* __restrict__ sarea,
    u64* __restrict__ mask, int* __restrict__ kept, int* __restrict__ num_kept,
    int* __restrict__ ctr) {
  __shared__ union {
    u64 slab[PANW * 8];                                // 32 KiB (scan)
    struct { float4 cbox[256]; float carea[256]; } m;  // 5 KiB (mask)
  } sh;
  __shared__ int keptGi[PAD];  // separate object: no alias with slab gloads
  int tid = threadIdx.x;

  if (blockIdx.x > 0) {
    // ================= mask worker =================
    int idx = (int)blockIdx.x - 1;
    int cb = idx >> 5, rg = idx & 31;  // cb-major: panel p done early
    if (4 * rg > cb) return;           // strictly lower-tri block
    int rbase = rg * 256;
    sh.m.cbox[tid] = sboxes[rbase + tid];
    sh.m.carea[tid] = sarea[rbase + tid];
    int lane = tid & 63, wid = tid >> 6;
    float4 bj = sboxes[cb * 64 + lane];
    float aB = sarea[cb * 64 + lane];
    __syncthreads();
    int rlim = cb * 64 + 64;
    int r0 = rbase + (wid << 6);
#pragma unroll 4
    for (int i = 0; i < 32; ++i) {
      int r1 = r0 + i, r2 = r0 + i + 32;
      if (r1 >= rlim) break;
      float4 bi1 = sh.m.cbox[(wid << 6) + i];
      float aA1 = sh.m.carea[(wid << 6) + i];
      float4 bi2 = sh.m.cbox[(wid << 6) + i + 32];
      float aA2 = sh.m.carea[(wid << 6) + i + 32];
      float lx1 = fmaxf(bi1.x, bj.x), ly1 = fmaxf(bi1.y, bj.y);
      float rx1 = fminf(bi1.z, bj.z), ry1 = fminf(bi1.w, bj.w);
      float in1 = fmaxf(rx1 - lx1, 0.0f) * fmaxf(ry1 - ly1, 0.0f);
      float u1 = aA1 + aB - in1 + 1e-8f;
      u64 bits1 = __ballot(((in1 * 33554432.0f - u1 * 16777216.0f) - u1) > 0.0f);
      float lx2 = fmaxf(bi2.x, bj.x), ly2 = fmaxf(bi2.y, bj.y);
      float rx2 = fminf(bi2.z, bj.z), ry2 = fminf(bi2.w, bj.w);
      float in2 = fmaxf(rx2 - lx2, 0.0f) * fmaxf(ry2 - ly2, 0.0f);
      float u2 = aA2 + aB - in2 + 1e-8f;
      u64 bits2 = __ballot(((in2 * 33554432.0f - u2 * 16777216.0f) - u2) > 0.0f);
      if ((r1 >> 6) == cb) bits1 &= ~((2ull << (r1 & 63)) - 1ull);  // j > r only
      if ((r2 >> 6) == cb) bits2 &= ~((2ull << (r2 & 63)) - 1ull);
      if (lane == 0) {
        __hip_atomic_store(&mask[(size_t)r1 * 128 + cb], bits1,
                           __ATOMIC_RELAXED, __HIP_MEMORY_SCOPE_AGENT);
        if (r2 < rlim)
          __hip_atomic_store(&mask[(size_t)r2 * 128 + cb], bits2,
                             __ATOMIC_RELAXED, __HIP_MEMORY_SCOPE_AGENT);
      }
    }
    __syncthreads();
    if (tid == 0)
      __hip_atomic_fetch_add(&ctr[cb >> 3], 1, __ATOMIC_RELEASE,
                             __HIP_MEMORY_SCOPE_AGENT);
    return;
  }

  // ================= scan block (wave 0 only) =================
  if (tid >= 64) return;
  int lane = tid;
  int cnt = 0;
  const char* mb = (const char*)mask;

  for (int p = 0; p < NPANEL; ++p) {
    int base = p * PANW;
    int need = 16 * p + 12;
    while (__hip_atomic_load(&ctr[p], __ATOMIC_RELAXED,
                             __HIP_MEMORY_SCOPE_AGENT) < need)
      __builtin_amdgcn_s_sleep(8);
    (void)__hip_atomic_load(&ctr[p], __ATOMIC_ACQUIRE,
                            __HIP_MEMORY_SCOPE_AGENT);  // invalidate caches

    // half-1 slab copy (rows base..base+256) + entry gather — one vmcnt window
    {
      const char* srcB = mb + (size_t)base * 1024 + (size_t)p * 64;
#pragma unroll
      for (int it = 0; it < 16; ++it) {
        const char* g = srcB + (size_t)(it * 16 + (lane >> 2)) * 1024 + (lane & 3) * 16;
        gload_lds16(g, &sh.slab[0] + it * 128);
      }
    }
    u64 acc = 0ull;
    for (int k = (lane >> 3); k < cnt; k += 8)
      acc |= mask[(size_t)keptGi[k] * 128 + p * 8 + (lane & 7)];

    asm volatile("s_waitcnt vmcnt(0)" ::: "memory");
    __builtin_amdgcn_sched_barrier(0);

    // half-2 copy (rows base+256..base+512): drained lazily on first w>=4
    {
      const char* srcB = mb + (size_t)(base + 256) * 1024 + (size_t)p * 64;
#pragma unroll
      for (int it = 0; it < 16; ++it) {
        const char* g = srcB + (size_t)(it * 16 + (lane >> 2)) * 1024 + (lane & 3) * 16;
        gload_lds16(g, &sh.slab[0] + (16 + it) * 128);
      }
    }

    acc |= __shfl_xor(acc, 8);
    acc |= __shfl_xor(acc, 16);
    acc |= __shfl_xor(acc, 32);
    u64 remv = acc;  // lane holds panel word (lane&7), self-bits added on consume
    const u64* sl = sh.slab;
    bool h2 = false;

    unsigned wm = (unsigned)__ballot(~remv != 0ull) & 0xFFu;  // words w/ candidates
    while (cnt < PAD && wm) {
      int w = __ffs(wm) - 1;
      if (w >= 4 && !h2) {  // rows >= 256 needed: half-2 must be resident
        asm volatile("s_waitcnt vmcnt(0)" ::: "memory");
        __builtin_amdgcn_sched_barrier(0);
        h2 = true;
      }
      u64 cur = __shfl(remv, w);  // fresh: includes all sA + consumed self-bits
      u64 inv = ~cur;             // nonzero by wm invariant
      // up to 4 candidate bits
      int b1 = __ffsll(inv) - 1;
      u64 i2 = inv & (inv - 1);
      int b2 = i2 ? (__ffsll(i2) - 1) : -1;
      u64 i3 = i2 ? (i2 & (i2 - 1)) : 0ull;
      int b3 = i3 ? (__ffsll(i3) - 1) : -1;
      u64 i4 = i3 ? (i3 & (i3 - 1)) : 0ull;
      int b4 = i4 ? (__ffsll(i4) - 1) : -1;
      int li1 = (w << 6) + b1;
      int li2 = (b2 >= 0) ? ((w << 6) + b2) : li1;
      int li3 = (b3 >= 0) ? ((w << 6) + b3) : li1;
      int li4 = (b4 >= 0) ? ((w << 6) + b4) : li1;
      // 8 independent ds_read_b64 — one latency window
      u64 mA1 = sl[li1 * 8 + w], sA1 = sl[li1 * 8 + (lane & 7)];
      u64 mA2 = sl[li2 * 8 + w], sA2 = sl[li2 * 8 + (lane & 7)];
      u64 mA3 = sl[li3 * 8 + w], sA3 = sl[li3 * 8 + (lane & 7)];
      u64 mA4 = sl[li4 * 8 + w], sA4 = sl[li4 * 8 + (lane & 7)];
      bool k2 = (b2 >= 0) && !((mA1 >> b2) & 1ull);
      bool k3 = (b3 >= 0) && !((mA1 >> b3) & 1ull) && !(k2 && ((mA2 >> b3) & 1ull));
      bool k4 = (b4 >= 0) && !((mA1 >> b4) & 1ull) && !(k2 && ((mA2 >> b4) & 1ull)) &&
                !(k3 && ((mA3 >> b4) & 1ull));
      u64 ownbits = 1ull << b1;  // valid keeps' self-bits (in no mask row)
      // commit sequentially with PAD guard
      if (lane == 0) kept[cnt] = base + li1;
      keptGi[cnt] = base + li1;
      cnt++;
      remv |= sA1;
      if (cnt < PAD && k2) {
        if (lane == 0) kept[cnt] = base + li2;
        keptGi[cnt] = base + li2;
        cnt++;
        remv |= sA2;
        ownbits |= 1ull << b2;
      }
      if (cnt < PAD && k3) {
        if (lane == 0) kept[cnt] = base + li3;
        keptGi[cnt] = base + li3;
        cnt++;
        remv |= sA3;
        ownbits |= 1ull << b3;
      }
      if (cnt < PAD && k4) {
        if (lane == 0) kept[cnt] = base + li4;
        keptGi[cnt] = base + li4;
        cnt++;
        remv |= sA4;
        ownbits |= 1ull << b4;
      }
      if ((lane & 7) == w) remv |= ownbits;
      wm = (unsigned)__ballot(~remv != 0ull) & 0xFFu;
    }
    if (cnt >= PAD) break;
  }
  asm volatile("s_waitcnt vmcnt(0)" ::: "memory");  // drain any outstanding copy
  if (lane == 0) *num_kept = cnt;
}

// ---------------- K5: gather outputs ----------------
__global__ __launch_bounds__(128) void gather_kernel(
    const int* __restrict__ kept, const int* __restrict__ num_kept_p,
    const int* __restrict__ sortedIdx, const float4* __restrict__ sortedBoxes,
    const float* __restrict__ scores, float* __restrict__ out) {
  int r = blockIdx.x;  // 0..299
  int t = threadIdx.x;
  float* boxes_out = out;             // (300,4)
  float* scores_out = out + PAD * 4;  // (300,81)
  int nk = *num_kept_p;
  bool valid = r < nk;
  int pos = valid ? kept[r] : 0;
  if (t < NCLS) {
    int orig = sortedIdx[pos];
    scores_out[(size_t)r * NCLS + t] = valid ? scores[(size_t)orig * NCLS + t] : 0.0f;
  }
  if (t == 96) {
    float4 b = sortedBoxes[pos];
    if (!valid) b = make_float4(0.f, 0.f, 0.f, 0.f);
    ((float4*)boxes_out)[r] = b;
  }
}

extern "C" void kernel_launch(void* const* d_in, const int* in_sizes, int n_in,
                              void* d_out, int out_size, void* d_ws, size_t ws_size,
                              hipStream_t stream) {
  const float* meta = (const float*)d_in[0];
  const float* deltas = (const float*)d_in[1];
  const float* proposals = (const float*)d_in[2];
  const float* scores = (const float*)d_in[3];
  float* out = (float*)d_out;
  char* ws = (char*)d_ws;

  float4* sel = (float4*)(ws + 0);               // 131072 B
  u64* keys = (u64*)(ws + 131072);               // 65536 B
  int* rank = (int*)(ws + 196608);               // 32768 B
  int* sortedIdx = (int*)(ws + 229376);          // 32768 B
  float4* sortedBoxes = (float4*)(ws + 262144);  // 131072 B
  float* sortedArea = (float*)(ws + 393216);     // 32768 B
  int* kept = (int*)(ws + 425984);               // 1200 B
  int* num_kept = (int*)(ws + 428032);           // 4 B
  int* ctr = (int*)(ws + 428096);                // 64 B
  u64* mask = (u64*)(ws + 458752);               // 8 MiB row-major

  decode_kernel<<<N / 32, 256, 0, stream>>>(meta, deltas, proposals, scores, sel, keys, rank, ctr);
  rank_kernel<<<dim3(N / 256, N / 256), 256, 0, stream>>>(keys, rank);
  scatter_kernel<<<N / 256, 256, 0, stream>>>(rank, sel, sortedIdx, sortedBoxes, sortedArea);
  mask_scan_kernel<<<1 + 128 * 32, 256, 0, stream>>>(sortedBoxes, sortedArea, mask, kept, num_kept, ctr);
  gather_kernel<<<PAD, 128, 0, stream>>>(kept, num_kept, sortedIdx, sortedBoxes, scores, out);
}

// Round 18
// 86.149 us; speedup vs baseline: 1.0281x; 1.0281x over previous
//
#include <hip/hip_runtime.h>

#define N 8192
#define NCLS 81
#define PAD 300
#define NPANEL 32
#define PANW 256

typedef unsigned long long u64;

__device__ __forceinline__ void gload_lds16(const void* g, void* l) {
  __builtin_amdgcn_global_load_lds(
      (const __attribute__((address_space(1))) unsigned int*)g,
      (__attribute__((address_space(3))) unsigned int*)l, 16, 0, 0);
}

// ---------------- K1: decode, 8 lanes per row + ctr/rank zero ----------------
__global__ __launch_bounds__(256) void decode_kernel(
    const float* __restrict__ meta, const float* __restrict__ deltas,
    const float* __restrict__ proposals, const float* __restrict__ scores,
    float4* __restrict__ sel, u64* __restrict__ keys, int* __restrict__ rank,
    int* __restrict__ ctr) {
  int tid = threadIdx.x;
  if (blockIdx.x == 0 && tid < 32) ctr[tid] = 0;  // col-panel counters (32 panels)
  int row = blockIdx.x * 32 + (tid >> 3);
  int sub = tid & 7;
  const float* srow = scores + (size_t)row * NCLS;
  float bs = -1e30f, ms = -1e30f;
  int best = 0;
  for (int c = sub; c < NCLS; c += 8) {
    float v = srow[c];
    if (v > bs) { bs = v; best = c; }
    if (c > 0) ms = fmaxf(ms, v);
  }
#pragma unroll
  for (int d = 1; d < 8; d <<= 1) {
    float ob = __shfl_xor(bs, d);
    int oi = __shfl_xor(best, d);
    float om = __shfl_xor(ms, d);
    if (ob > bs || (ob == bs && oi < best)) { bs = ob; best = oi; }
    ms = fmaxf(ms, om);
  }
  if (sub == 0) {
    float W = meta[1], sc = meta[2], H = meta[0];
    const float* p = proposals + row * 4;
    float x1 = p[0] / sc, y1 = p[1] / sc, x2 = p[2] / sc, y2 = p[3] / sc;
    float w = x2 - x1 + 1.0f, h = y2 - y1 + 1.0f;
    float cx = x1 + 0.5f * w, cy = y1 + 0.5f * h;
    float4 d4 = *(const float4*)(deltas + (size_t)row * (4 * NCLS) + best * 4);
    float pcx = d4.x * w + cx, pcy = d4.y * h + cy;
    float pw = expf(d4.z) * w, ph = expf(d4.w) * h;
    float lx = W - 1.0f, ly = H - 1.0f;
    float ox1 = fminf(fmaxf(pcx - 0.5f * pw, 0.0f), lx);
    float oy1 = fminf(fmaxf(pcy - 0.5f * ph, 0.0f), ly);
    float ox2 = fminf(fmaxf(pcx + 0.5f * pw, 0.0f), lx);
    float oy2 = fminf(fmaxf(pcy + 0.5f * ph, 0.0f), ly);
    sel[row] = make_float4(ox1, oy1, ox2, oy2);
    keys[row] = ((u64)(~__float_as_uint(ms)) << 32) | (unsigned)row;
    rank[row] = 0;
  }
}

// ---------------- K2a: brute-force rank, LDS-tiled ----------------
__global__ __launch_bounds__(256) void rank_kernel(
    const u64* __restrict__ keys, int* __restrict__ rank) {
  __shared__ u64 kt[256];
  int tid = threadIdx.x;
  int i = blockIdx.x * 256 + tid;
  kt[tid] = keys[blockIdx.y * 256 + tid];
  u64 ki = keys[i];
  __syncthreads();
  int c = 0;
#pragma unroll 8
  for (int t = 0; t < 256; ++t) c += (kt[t] < ki);
  atomicAdd(&rank[i], c);
}

// ---------------- K2b: scatter into sorted order (+ exact area) ----------------
__global__ __launch_bounds__(256) void scatter_kernel(
    const int* __restrict__ rank, const float4* __restrict__ sel,
    int* __restrict__ sortedIdx, float4* __restrict__ sortedBoxes,
    float* __restrict__ sortedArea) {
  int i = blockIdx.x * 256 + threadIdx.x;
  int r = rank[i];
  float4 b = sel[i];
  sortedIdx[r] = i;
  sortedBoxes[r] = b;
  sortedArea[r] = fmaxf(b.z - b.x, 0.0f) * fmaxf(b.w - b.y, 0.0f);
}

// ---------------- K3+K4 fused: mask workers + gated greedy scan ----------------
// R16 structure with PANW 512->256 (NPANEL=32): slab shrinks 32KB->8KB so the
// kernel's LDS footprint (~9.4KB) no longer throttles WORKER occupancy — R16's
// 13.6% occupancy was the union slab capping workers at ~4 blocks/CU; now 8
// blocks/CU (wave-limited), mask wavefront ~2x faster. Total ~= mask_total +
// scan tail, so this attacks the binding term. Scan geometry: 4 words/panel
// (remv over lane&3, wm 4-bit, gather stride-16, need[p]=4p+4, ctr[32]).
// Coherence proven (R14-16): agent-scope word stores + release ctr; scan polls
// relaxed + acquire per gate, OFF the keep chain. Poison re-derived for 4-word
// geometry: diagonal word always computed; sub-diagonal slab poison ORs only
// into exhausted wm words; gather rows strictly upper-tri. Workers never wait.
__global__ __launch_bounds__(256) void mask_scan_kernel(
    const float4* __restrict__ sboxes, const float* __restrict__ sarea,
    u64* __restrict__ mask, int* __restrict__ kept, int* __restrict__ num_kept,
    int* __restrict__ ctr) {
  __shared__ union {
    u64 slab[PANW * 4];                                // 8 KiB (scan)
    struct { float4 cbox[256]; float carea[256]; } m;  // 5 KiB (mask)
  } sh;
  __shared__ int keptGi[PAD];
  int tid = threadIdx.x;

  if (blockIdx.x > 0) {
    // ================= mask worker (R15-proven, ctr idx cb>>2) =================
    int idx = (int)blockIdx.x - 1;
    int cb = idx >> 5, rg = idx & 31;  // cb-major: panel p done early
    if (4 * rg > cb) return;           // strictly lower-tri block
    int rbase = rg * 256;
    sh.m.cbox[tid] = sboxes[rbase + tid];
    sh.m.carea[tid] = sarea[rbase + tid];
    int lane = tid & 63, wid = tid >> 6;
    float4 bj = sboxes[cb * 64 + lane];
    float aB = sarea[cb * 64 + lane];
    __syncthreads();
    int rlim = cb * 64 + 64;
    int r0 = rbase + (wid << 6);
#pragma unroll 4
    for (int i = 0; i < 32; ++i) {
      int r1 = r0 + i, r2 = r0 + i + 32;
      if (r1 >= rlim) break;
      float4 bi1 = sh.m.cbox[(wid << 6) + i];
      float aA1 = sh.m.carea[(wid << 6) + i];
      float4 bi2 = sh.m.cbox[(wid << 6) + i + 32];
      float aA2 = sh.m.carea[(wid << 6) + i + 32];
      float lx1 = fmaxf(bi1.x, bj.x), ly1 = fmaxf(bi1.y, bj.y);
      float rx1 = fminf(bi1.z, bj.z), ry1 = fminf(bi1.w, bj.w);
      float in1 = fmaxf(rx1 - lx1, 0.0f) * fmaxf(ry1 - ly1, 0.0f);
      float u1 = aA1 + aB - in1 + 1e-8f;
      u64 bits1 = __ballot(((in1 * 33554432.0f - u1 * 16777216.0f) - u1) > 0.0f);
      float lx2 = fmaxf(bi2.x, bj.x), ly2 = fmaxf(bi2.y, bj.y);
      float rx2 = fminf(bi2.z, bj.z), ry2 = fminf(bi2.w, bj.w);
      float in2 = fmaxf(rx2 - lx2, 0.0f) * fmaxf(ry2 - ly2, 0.0f);
      float u2 = aA2 + aB - in2 + 1e-8f;
      u64 bits2 = __ballot(((in2 * 33554432.0f - u2 * 16777216.0f) - u2) > 0.0f);
      if ((r1 >> 6) == cb) bits1 &= ~((2ull << (r1 & 63)) - 1ull);  // j > r only
      if ((r2 >> 6) == cb) bits2 &= ~((2ull << (r2 & 63)) - 1ull);
      if (lane == 0) {
        __hip_atomic_store(&mask[(size_t)r1 * 128 + cb], bits1,
                           __ATOMIC_RELAXED, __HIP_MEMORY_SCOPE_AGENT);
        if (r2 < rlim)
          __hip_atomic_store(&mask[(size_t)r2 * 128 + cb], bits2,
                             __ATOMIC_RELAXED, __HIP_MEMORY_SCOPE_AGENT);
      }
    }
    __syncthreads();
    if (tid == 0)
      __hip_atomic_fetch_add(&ctr[cb >> 2], 1, __ATOMIC_RELEASE,
                             __HIP_MEMORY_SCOPE_AGENT);
    return;
  }

  // ================= scan block (wave 0 only) =================
  if (tid >= 64) return;
  int lane = tid;
  int cnt = 0;
  const char* mb = (const char*)mask;

  for (int p = 0; p < NPANEL; ++p) {
    int base = p * PANW;
    int need = 4 * p + 4;  // workers covering col-panel p (cb in [4p,4p+4))
    while (__hip_atomic_load(&ctr[p], __ATOMIC_RELAXED,
                             __HIP_MEMORY_SCOPE_AGENT) < need)
      __builtin_amdgcn_s_sleep(8);
    (void)__hip_atomic_load(&ctr[p], __ATOMIC_ACQUIRE,
                            __HIP_MEMORY_SCOPE_AGENT);  // invalidate caches

    // slab copy (256 rows x 32B) + entry gather — one vmcnt window
    {
      const char* srcB = mb + (size_t)base * 1024 + (size_t)p * 32;
#pragma unroll
      for (int it = 0; it < 8; ++it) {
        const char* g = srcB + (size_t)(it * 32 + (lane >> 1)) * 1024 + (lane & 1) * 16;
        gload_lds16(g, &sh.slab[0] + it * 128);
      }
    }
    u64 acc = 0ull;
    for (int k = (lane >> 2); k < cnt; k += 16)
      acc |= mask[(size_t)keptGi[k] * 128 + p * 4 + (lane & 3)];

    asm volatile("s_waitcnt vmcnt(0)" ::: "memory");
    __builtin_amdgcn_sched_barrier(0);

    acc |= __shfl_xor(acc, 4);
    acc |= __shfl_xor(acc, 8);
    acc |= __shfl_xor(acc, 16);
    acc |= __shfl_xor(acc, 32);
    u64 remv = acc;  // lane holds panel word (lane&3); self-bits added on consume
    const u64* sl = sh.slab;

    unsigned wm = (unsigned)__ballot(~remv != 0ull) & 0xFu;  // words w/ candidates
    while (cnt < PAD && wm) {
      int w = __ffs(wm) - 1;
      u64 cur = __shfl(remv, w);  // lane w holds word w (w<4)
      u64 inv = ~cur;             // nonzero by wm invariant
      int b1 = __ffsll(inv) - 1;
      u64 i2 = inv & (inv - 1);
      int b2 = i2 ? (__ffsll(i2) - 1) : -1;
      u64 i3 = i2 ? (i2 & (i2 - 1)) : 0ull;
      int b3 = i3 ? (__ffsll(i3) - 1) : -1;
      u64 i4 = i3 ? (i3 & (i3 - 1)) : 0ull;
      int b4 = i4 ? (__ffsll(i4) - 1) : -1;
      int li1 = (w << 6) + b1;
      int li2 = (b2 >= 0) ? ((w << 6) + b2) : li1;
      int li3 = (b3 >= 0) ? ((w << 6) + b3) : li1;
      int li4 = (b4 >= 0) ? ((w << 6) + b4) : li1;
      // 8 independent ds_read_b64 — one latency window
      u64 mA1 = sl[li1 * 4 + w], sA1 = sl[li1 * 4 + (lane & 3)];
      u64 mA2 = sl[li2 * 4 + w], sA2 = sl[li2 * 4 + (lane & 3)];
      u64 mA3 = sl[li3 * 4 + w], sA3 = sl[li3 * 4 + (lane & 3)];
      u64 mA4 = sl[li4 * 4 + w], sA4 = sl[li4 * 4 + (lane & 3)];
      bool k2 = (b2 >= 0) && !((mA1 >> b2) & 1ull);
      bool k3 = (b3 >= 0) && !((mA1 >> b3) & 1ull) && !(k2 && ((mA2 >> b3) & 1ull));
      bool k4 = (b4 >= 0) && !((mA1 >> b4) & 1ull) && !(k2 && ((mA2 >> b4) & 1ull)) &&
                !(k3 && ((mA3 >> b4) & 1ull));
      u64 ownbits = 1ull << b1;  // valid keeps' self-bits (in no mask row)
      if (lane == 0) kept[cnt] = base + li1;
      keptGi[cnt] = base + li1;
      cnt++;
      remv |= sA1;
      if (cnt < PAD && k2) {
        if (lane == 0) kept[cnt] = base + li2;
        keptGi[cnt] = base + li2;
        cnt++;
        remv |= sA2;
        ownbits |= 1ull << b2;
      }
      if (cnt < PAD && k3) {
        if (lane == 0) kept[cnt] = base + li3;
        keptGi[cnt] = base + li3;
        cnt++;
        remv |= sA3;
        ownbits |= 1ull << b3;
      }
      if (cnt < PAD && k4) {
        if (lane == 0) kept[cnt] = base + li4;
        keptGi[cnt] = base + li4;
        cnt++;
        remv |= sA4;
        ownbits |= 1ull << b4;
      }
      if ((lane & 3) == w) remv |= ownbits;
      wm = (unsigned)__ballot(~remv != 0ull) & 0xFu;
    }
    if (cnt >= PAD) break;
  }
  asm volatile("s_waitcnt vmcnt(0)" ::: "memory");  // drain any outstanding copy
  if (lane == 0) *num_kept = cnt;
}

// ---------------- K5: gather outputs ----------------
__global__ __launch_bounds__(128) void gather_kernel(
    const int* __restrict__ kept, const int* __restrict__ num_kept_p,
    const int* __restrict__ sortedIdx, const float4* __restrict__ sortedBoxes,
    const float* __restrict__ scores, float* __restrict__ out) {
  int r = blockIdx.x;  // 0..299
  int t = threadIdx.x;
  float* boxes_out = out;             // (300,4)
  float* scores_out = out + PAD * 4;  // (300,81)
  int nk = *num_kept_p;
  bool valid = r < nk;
  int pos = valid ? kept[r] : 0;
  if (t < NCLS) {
    int orig = sortedIdx[pos];
    scores_out[(size_t)r * NCLS + t] = valid ? scores[(size_t)orig * NCLS + t] : 0.0f;
  }
  if (t == 96) {
    float4 b = sortedBoxes[pos];
    if (!valid) b = make_float4(0.f, 0.f, 0.f, 0.f);
    ((float4*)boxes_out)[r] = b;
  }
}

extern "C" void kernel_launch(void* const* d_in, const int* in_sizes, int n_in,
                              void* d_out, int out_size, void* d_ws, size_t ws_size,
                              hipStream_t stream) {
  const float* meta = (const float*)d_in[0];
  const float* deltas = (const float*)d_in[1];
  const float* proposals = (const float*)d_in[2];
  const float* scores = (const float*)d_in[3];
  float* out = (float*)d_out;
  char* ws = (char*)d_ws;

  float4* sel = (float4*)(ws + 0);               // 131072 B
  u64* keys = (u64*)(ws + 131072);               // 65536 B
  int* rank = (int*)(ws + 196608);               // 32768 B
  int* sortedIdx = (int*)(ws + 229376);          // 32768 B
  float4* sortedBoxes = (float4*)(ws + 262144);  // 131072 B
  float* sortedArea = (float*)(ws + 393216);     // 32768 B
  int* kept = (int*)(ws + 425984);               // 1200 B
  int* num_kept = (int*)(ws + 428032);           // 4 B
  int* ctr = (int*)(ws + 428096);                // 128 B
  u64* mask = (u64*)(ws + 458752);               // 8 MiB row-major

  decode_kernel<<<N / 32, 256, 0, stream>>>(meta, deltas, proposals, scores, sel, keys, rank, ctr);
  rank_kernel<<<dim3(N / 256, N / 256), 256, 0, stream>>>(keys, rank);
  scatter_kernel<<<N / 256, 256, 0, stream>>>(rank, sel, sortedIdx, sortedBoxes, sortedArea);
  mask_scan_kernel<<<1 + 128 * 32, 256, 0, stream>>>(sortedBoxes, sortedArea, mask, kept, num_kept, ctr);
  gather_kernel<<<PAD, 128, 0, stream>>>(kept, num_kept, sortedIdx, sortedBoxes, scores, out);
}